// Round 12
// baseline (903.759 us; speedup 1.0000x reference)
//
#include <hip/hip_runtime.h>
#include <hip/hip_bf16.h>
#include <math.h>

#define NN   10000
#define EE   160000
#define CC   128
#define RBFD 20
#define HIDD 32
#define WND  384
#define MROW 1152   // 9*128 accumulator row
#define RS   384    // sorted u-row stride (floats) = 1536 B, line-aligned

// Static device buffers (fully rewritten each call).
__device__ __align__(16) float g_row[(size_t)EE * RS];    // 245.8 MB: sorted u=[u0|u1|u2]
__device__ __align__(16) float g_proj[(size_t)NN * 64];   // 2.6 MB: Pi(32,+bs1)|Pj(32)
__device__ __align__(16) float g_accu[(size_t)NN * MROW]; // 46 MB
__device__ int g_deg[NN];
__device__ int g_offs[NN + 1];
__device__ int g_rel[EE];
__device__ int g_ord[EE];   // sorted row -> original edge

__device__ __forceinline__ float silu_f(float x) { return x / (1.f + __expf(-x)); }

__global__ __launch_bounds__(256) void zero_deg_kernel()
{
    int i = blockIdx.x * 256 + threadIdx.x;
    if (i < NN) g_deg[i] = 0;
}

__global__ __launch_bounds__(256) void hist_kernel(const int* __restrict__ edge_index)
{
    int e = blockIdx.x * 256 + threadIdx.x;
    if (e < EE) g_rel[e] = atomicAdd(&g_deg[edge_index[e]], 1);
}

// Blocked scan: 256 threads x 40 items, one block.
__global__ __launch_bounds__(256) void scan_kernel()
{
    __shared__ int sP[256];
    int t = threadIdx.x;
    int lo = t * 40, hi = min(lo + 40, NN);
    int sum = 0;
    for (int i = lo; i < hi; ++i) sum += g_deg[i];
    sP[t] = sum;
    __syncthreads();
    for (int off = 1; off < 256; off <<= 1) {
        int v = (t >= off) ? sP[t - off] : 0;
        __syncthreads();
        sP[t] += v;
        __syncthreads();
    }
    int run = sP[t] - sum;   // exclusive prefix
    if (t == 0) g_offs[0] = 0;
    for (int i = lo; i < hi; ++i) { run += g_deg[i]; g_offs[i + 1] = run; }
}

__global__ __launch_bounds__(256) void perm_kernel(const int* __restrict__ edge_index)
{
    int e = blockIdx.x * 256 + threadIdx.x;
    if (e < EE) g_ord[g_offs[edge_index[e]] + g_rel[e]] = e;
}

// Per-node halves of MLP1: Pi = nf@Ws1[0:128]+bs1, Pj = nf@Ws1[128:256].
__global__ __launch_bounds__(64) void proj_kernel(
    const float* __restrict__ nf,
    const float* __restrict__ Ws1, const float* __restrict__ bs1)
{
    int n = blockIdx.x * 64 + threadIdx.x;
    if (n >= NN) return;
    float Pi[HIDD], Pj[HIDD];
    #pragma unroll
    for (int j = 0; j < HIDD; ++j) { Pi[j] = bs1[j]; Pj[j] = 0.f; }
    const float4* x4 = reinterpret_cast<const float4*>(nf + (size_t)n * CC);
    #pragma unroll 1
    for (int k4 = 0; k4 < CC / 4; ++k4) {
        float4 a = x4[k4];
        const float* wi = Ws1 + (4 * k4) * HIDD;
        const float* wj = Ws1 + (CC + 4 * k4) * HIDD;
        #pragma unroll
        for (int j = 0; j < HIDD; ++j) {
            Pi[j] = fmaf(a.x, wi[j], Pi[j]);
            Pi[j] = fmaf(a.y, wi[HIDD + j], Pi[j]);
            Pi[j] = fmaf(a.z, wi[2 * HIDD + j], Pi[j]);
            Pi[j] = fmaf(a.w, wi[3 * HIDD + j], Pi[j]);
            Pj[j] = fmaf(a.x, wj[j], Pj[j]);
            Pj[j] = fmaf(a.y, wj[HIDD + j], Pj[j]);
            Pj[j] = fmaf(a.z, wj[2 * HIDD + j], Pj[j]);
            Pj[j] = fmaf(a.w, wj[3 * HIDD + j], Pj[j]);
        }
    }
    float* o = g_proj + (size_t)n * 64;
    #pragma unroll
    for (int j = 0; j < HIDD; ++j) { o[j] = Pi[j]; o[HIDD + j] = Pj[j]; }
}

__device__ __forceinline__ void edge_hidden(
    int e, int s, int t,
    const float* __restrict__ edge_attr,
    const float* __restrict__ Wr1, const float* __restrict__ br1,
    float (&hs)[HIDD], float (&hr)[HIDD])
{
    const float4* pi = reinterpret_cast<const float4*>(g_proj + (size_t)s * 64);
    const float4* pj = reinterpret_cast<const float4*>(g_proj + (size_t)t * 64 + HIDD);
    #pragma unroll
    for (int j4 = 0; j4 < HIDD / 4; ++j4) {
        float4 a = pi[j4], b = pj[j4];
        hs[4 * j4 + 0] = silu_f(a.x + b.x);
        hs[4 * j4 + 1] = silu_f(a.y + b.y);
        hs[4 * j4 + 2] = silu_f(a.z + b.z);
        hs[4 * j4 + 3] = silu_f(a.w + b.w);
    }
    #pragma unroll
    for (int j = 0; j < HIDD; ++j) hr[j] = br1[j];
    #pragma unroll 1
    for (int k4 = 0; k4 < RBFD / 4; ++k4) {
        float4 a = reinterpret_cast<const float4*>(edge_attr + (size_t)e * RBFD)[k4];
        const float* wp = Wr1 + (4 * k4) * HIDD;
        #pragma unroll
        for (int j = 0; j < HIDD; ++j) {
            hr[j] = fmaf(a.x, wp[j], hr[j]);
            hr[j] = fmaf(a.y, wp[HIDD + j], hr[j]);
            hr[j] = fmaf(a.z, wp[2 * HIDD + j], hr[j]);
            hr[j] = fmaf(a.w, wp[3 * HIDD + j], hr[j]);
        }
    }
    #pragma unroll
    for (int j = 0; j < HIDD; ++j) hr[j] = silu_f(hr[j]);
}

// Edge MLP2, sorted order, 2 edges per lane (wave = 128 edges, block = 256).
// Weights staged per 32-col chunk in LDS; each broadcast b128 weight read
// feeds 8 FMAs (2 edges x 4 cols). Full-line 128B row dump via sT.
__global__ __launch_bounds__(128) void mlp_kernel(
    const float* __restrict__ nf,
    const float* __restrict__ edge_attr,
    const int*   __restrict__ edge_index,
    const float* __restrict__ Ws2, const float* __restrict__ bs2,
    const float* __restrict__ Wr1, const float* __restrict__ br1,
    const float* __restrict__ Wr2, const float* __restrict__ br2)
{
    __shared__ float sW[2][32][36];    // 9.2 KB
    __shared__ float sT[2][128][33];   // 33.8 KB: per-wave 128-edge x 32-col u

    int w = threadIdx.x >> 6, l = threadIdx.x & 63;
    int base = blockIdx.x * 256 + w * 128;    // grid exact: EE/256
    int pA = base + l, pB = base + 64 + l;
    int eA = g_ord[pA], eB = g_ord[pB];
    int sA = edge_index[eA], tA = edge_index[EE + eA];
    int sB = edge_index[eB], tB = edge_index[EE + eB];

    float hsA[HIDD], hrA[HIDD], hsB[HIDD], hrB[HIDD];
    edge_hidden(eA, sA, tA, edge_attr, Wr1, br1, hsA, hrA);
    edge_hidden(eB, sB, tB, edge_attr, Wr1, br1, hsB, hrB);

    const float4* nf4 = reinterpret_cast<const float4*>(nf);
    size_t rowbase = (size_t)base * RS;
    int jj = (threadIdx.x >> 1) & 31, qq = threadIdx.x & 1;   // staging decomp

    #pragma unroll 1
    for (int ch = 0; ch < 12; ++ch) {
        int c0 = ch * 32;
        int xb = (c0 & (CC - 1)) >> 2;
        __syncthreads();   // prior chunk's sW reads + sT dump complete
        {
            int mat = threadIdx.x >> 6;
            const float4* src = reinterpret_cast<const float4*>(
                (mat ? Wr2 : Ws2) + (size_t)jj * WND + c0 + qq * 16);
            float4* dst = reinterpret_cast<float4*>(&sW[mat][jj][qq * 16]);
            dst[0] = src[0]; dst[1] = src[1]; dst[2] = src[2]; dst[3] = src[3];
        }
        __syncthreads();

        #pragma unroll
        for (int c4 = 0; c4 < 8; ++c4) {
            float4 xjA4 = nf4[(size_t)tA * (CC / 4) + xb + c4];
            float4 xjB4 = nf4[(size_t)tB * (CC / 4) + xb + c4];
            float bsv0 = bs2[c0 + c4 * 4 + 0], bsv1 = bs2[c0 + c4 * 4 + 1];
            float bsv2 = bs2[c0 + c4 * 4 + 2], bsv3 = bs2[c0 + c4 * 4 + 3];
            float brv0 = br2[c0 + c4 * 4 + 0], brv1 = br2[c0 + c4 * 4 + 1];
            float brv2 = br2[c0 + c4 * 4 + 2], brv3 = br2[c0 + c4 * 4 + 3];
            float aA0 = bsv0, aA1 = bsv1, aA2 = bsv2, aA3 = bsv3;
            float rA0 = brv0, rA1 = brv1, rA2 = brv2, rA3 = brv3;
            float aB0 = bsv0, aB1 = bsv1, aB2 = bsv2, aB3 = bsv3;
            float rB0 = brv0, rB1 = brv1, rB2 = brv2, rB3 = brv3;
            #pragma unroll
            for (int jg = 0; jg < 8; ++jg) {
                float4 wv[4], rv[4];
                #pragma unroll
                for (int k = 0; k < 4; ++k) {
                    wv[k] = *reinterpret_cast<const float4*>(&sW[0][jg * 4 + k][c4 * 4]);
                    rv[k] = *reinterpret_cast<const float4*>(&sW[1][jg * 4 + k][c4 * 4]);
                }
                #pragma unroll
                for (int k = 0; k < 4; ++k) {
                    float hA = hsA[jg * 4 + k], hB = hsB[jg * 4 + k];
                    aA0 = fmaf(hA, wv[k].x, aA0); aA1 = fmaf(hA, wv[k].y, aA1);
                    aA2 = fmaf(hA, wv[k].z, aA2); aA3 = fmaf(hA, wv[k].w, aA3);
                    aB0 = fmaf(hB, wv[k].x, aB0); aB1 = fmaf(hB, wv[k].y, aB1);
                    aB2 = fmaf(hB, wv[k].z, aB2); aB3 = fmaf(hB, wv[k].w, aB3);
                    float gA = hrA[jg * 4 + k], gB = hrB[jg * 4 + k];
                    rA0 = fmaf(gA, rv[k].x, rA0); rA1 = fmaf(gA, rv[k].y, rA1);
                    rA2 = fmaf(gA, rv[k].z, rA2); rA3 = fmaf(gA, rv[k].w, rA3);
                    rB0 = fmaf(gB, rv[k].x, rB0); rB1 = fmaf(gB, rv[k].y, rB1);
                    rB2 = fmaf(gB, rv[k].z, rB2); rB3 = fmaf(gB, rv[k].w, rB3);
                }
            }
            sT[w][l][c4 * 4 + 0]      = aA0 * rA0 * xjA4.x;
            sT[w][l][c4 * 4 + 1]      = aA1 * rA1 * xjA4.y;
            sT[w][l][c4 * 4 + 2]      = aA2 * rA2 * xjA4.z;
            sT[w][l][c4 * 4 + 3]      = aA3 * rA3 * xjA4.w;
            sT[w][64 + l][c4 * 4 + 0] = aB0 * rB0 * xjB4.x;
            sT[w][64 + l][c4 * 4 + 1] = aB1 * rB1 * xjB4.y;
            sT[w][64 + l][c4 * 4 + 2] = aB2 * rB2 * xjB4.z;
            sT[w][64 + l][c4 * 4 + 3] = aB3 * rB3 * xjB4.w;
        }

        // per-wave dump: 128 rows x 128B full lines (wave-lockstep, in-order DS)
        int rr = l >> 3, kk = l & 7;
        #pragma unroll
        for (int it = 0; it < 16; ++it) {
            int r = it * 8 + rr;
            float4 v = make_float4(sT[w][r][kk * 4 + 0], sT[w][r][kk * 4 + 1],
                                   sT[w][r][kk * 4 + 2], sT[w][r][kk * 4 + 3]);
            *reinterpret_cast<float4*>(&g_row[rowbase + (size_t)r * RS + c0 + kk * 4]) = v;
        }
    }
}

// Streaming segmented sum: wave per node, lane = 2 channels. (unchanged)
__global__ __launch_bounds__(512) void gather_kernel(const float* __restrict__ edge_rsh)
{
    int wv = threadIdx.x >> 6, l = threadIdx.x & 63;
    int n = blockIdx.x * 8 + wv;                 // grid exact: NN/8
    int beg = g_offs[n], end = g_offs[n + 1];

    float acc[9][2] = {};
    int r = beg;
    for (; r + 1 < end; r += 2) {
        const float* R0 = g_row + (size_t)r * RS;
        const float* R1 = R0 + RS;
        int e0 = g_ord[r], e1 = g_ord[r + 1];
        const float* Y0 = edge_rsh + (size_t)e0 * 9;
        const float* Y1 = edge_rsh + (size_t)e1 * 9;
        float a0 = R0[l], a1 = R0[64 + l], a2 = R0[128 + l];
        float a3 = R0[192 + l], a4 = R0[256 + l], a5 = R0[320 + l];
        float b0 = R1[l], b1 = R1[64 + l], b2 = R1[128 + l];
        float b3 = R1[192 + l], b4 = R1[256 + l], b5 = R1[320 + l];
        #pragma unroll
        for (int k = 0; k < 9; ++k) {
            float y0 = Y0[k], y1 = Y1[k];
            float ua = (k == 0) ? a0 : (k < 4) ? a2 : a4;
            float ub = (k == 0) ? a1 : (k < 4) ? a3 : a5;
            float va = (k == 0) ? b0 : (k < 4) ? b2 : b4;
            float vb = (k == 0) ? b1 : (k < 4) ? b3 : b5;
            acc[k][0] = fmaf(ua, y0, acc[k][0]);
            acc[k][1] = fmaf(ub, y0, acc[k][1]);
            acc[k][0] = fmaf(va, y1, acc[k][0]);
            acc[k][1] = fmaf(vb, y1, acc[k][1]);
        }
    }
    if (r < end) {
        const float* R0 = g_row + (size_t)r * RS;
        int e0 = g_ord[r];
        const float* Y0 = edge_rsh + (size_t)e0 * 9;
        float a0 = R0[l], a1 = R0[64 + l], a2 = R0[128 + l];
        float a3 = R0[192 + l], a4 = R0[256 + l], a5 = R0[320 + l];
        #pragma unroll
        for (int k = 0; k < 9; ++k) {
            float y0 = Y0[k];
            float ua = (k == 0) ? a0 : (k < 4) ? a2 : a4;
            float ub = (k == 0) ? a1 : (k < 4) ? a3 : a5;
            acc[k][0] = fmaf(ua, y0, acc[k][0]);
            acc[k][1] = fmaf(ub, y0, acc[k][1]);
        }
    }

    float* A = g_accu + (size_t)n * MROW;
    #pragma unroll
    for (int m = 0; m < 9; ++m) {
        A[m * CC + l]      = acc[m][0];
        A[m * CC + 64 + l] = acc[m][1];
    }
}

// Node-wise linear, 2 nodes per block. (unchanged)
__global__ __launch_bounds__(256) void lin2_kernel(
    const float* __restrict__ W0, const float* __restrict__ b0,
    const float* __restrict__ W1, const float* __restrict__ W2,
    float* __restrict__ out)
{
    __shared__ float sA[2 * MROW];
    int n0 = blockIdx.x * 2;
    const float4* g = reinterpret_cast<const float4*>(g_accu + (size_t)n0 * MROW);
    for (int i = threadIdx.x; i < 2 * MROW / 4; i += 256)
        reinterpret_cast<float4*>(sA)[i] = g[i];
    __syncthreads();

    int d  = threadIdx.x & (CC - 1);
    int nl = threadIdx.x >> 7;
    const float* a = sA + nl * MROW;

    float acc[9];
    #pragma unroll
    for (int m = 0; m < 9; ++m) acc[m] = 0.f;

    #pragma unroll 2
    for (int cc = 0; cc < CC; ++cc) {
        float w0 = W0[cc * CC + d];
        float w1 = W1[cc * CC + d];
        float w2 = W2[cc * CC + d];
        acc[0] = fmaf(a[cc],           w0, acc[0]);
        acc[1] = fmaf(a[CC + cc],      w1, acc[1]);
        acc[2] = fmaf(a[2 * CC + cc],  w1, acc[2]);
        acc[3] = fmaf(a[3 * CC + cc],  w1, acc[3]);
        acc[4] = fmaf(a[4 * CC + cc],  w2, acc[4]);
        acc[5] = fmaf(a[5 * CC + cc],  w2, acc[5]);
        acc[6] = fmaf(a[6 * CC + cc],  w2, acc[6]);
        acc[7] = fmaf(a[7 * CC + cc],  w2, acc[7]);
        acc[8] = fmaf(a[8 * CC + cc],  w2, acc[8]);
    }

    const float inv = 0.08838834764831845f;  // 1/sqrt(128)
    size_t ob = (size_t)(n0 + nl) * MROW;
    out[ob + d] = acc[0] * inv + b0[d];
    #pragma unroll
    for (int m = 0; m < 3; ++m) out[ob + CC + d * 3 + m]     = acc[1 + m] * inv;
    #pragma unroll
    for (int m = 0; m < 5; ++m) out[ob + 4 * CC + d * 5 + m] = acc[4 + m] * inv;
}

extern "C" void kernel_launch(void* const* d_in, const int* in_sizes, int n_in,
                              void* d_out, int out_size, void* d_ws, size_t ws_size,
                              hipStream_t stream)
{
    const float* node_feat  = (const float*)d_in[0];
    const float* edge_attr  = (const float*)d_in[1];
    const float* edge_rsh   = (const float*)d_in[2];
    const int*   edge_index = (const int*)  d_in[3];
    const float* Ws1 = (const float*)d_in[4];
    const float* bs1 = (const float*)d_in[5];
    const float* Ws2 = (const float*)d_in[6];
    const float* bs2 = (const float*)d_in[7];
    const float* Wr1 = (const float*)d_in[8];
    const float* br1 = (const float*)d_in[9];
    const float* Wr2 = (const float*)d_in[10];
    const float* br2 = (const float*)d_in[11];
    const float* W0  = (const float*)d_in[12];
    const float* b0  = (const float*)d_in[13];
    const float* W1  = (const float*)d_in[14];
    const float* W2  = (const float*)d_in[15];
    float* out = (float*)d_out;

    zero_deg_kernel<<<(NN + 255) / 256, 256, 0, stream>>>();
    hist_kernel<<<EE / 256, 256, 0, stream>>>(edge_index);
    scan_kernel<<<1, 256, 0, stream>>>();
    perm_kernel<<<EE / 256, 256, 0, stream>>>(edge_index);
    proj_kernel<<<(NN + 63) / 64, 64, 0, stream>>>(node_feat, Ws1, bs1);
    mlp_kernel<<<EE / 256, 128, 0, stream>>>(
        node_feat, edge_attr, edge_index, Ws2, bs2, Wr1, br1, Wr2, br2);
    gather_kernel<<<NN / 8, 512, 0, stream>>>(edge_rsh);
    lin2_kernel<<<NN / 2, 256, 0, stream>>>(W0, b0, W1, W2, out);
}

// Round 13
// 366.884 us; speedup vs baseline: 2.4633x; 2.4633x over previous
//
#include <hip/hip_runtime.h>
#include <hip/hip_bf16.h>
#include <math.h>

#define NN   10000
#define EE   160000
#define CC   128
#define RBFD 20
#define HIDD 32
#define WND  384
#define MROW 1152   // 9*128 accumulator row: [m=0..8][c=0..127]

// Static device buffers (fully rewritten each call).
__device__ __align__(16) float g_proj[(size_t)NN * 64];   // 2.6 MB: Pi(32,+bs1)|Pj(32)
__device__ __align__(16) float g_accu[(size_t)NN * MROW]; // 46 MB, atomically accumulated
__device__ int g_deg[NN];
__device__ int g_offs[NN + 1];
__device__ int g_rel[EE];
__device__ int g_ord[EE];   // sorted row -> original edge

__device__ __forceinline__ float silu_f(float x) { return x / (1.f + __expf(-x)); }

__global__ __launch_bounds__(256) void zero_deg_kernel()
{
    int i = blockIdx.x * 256 + threadIdx.x;
    if (i < NN) g_deg[i] = 0;
}

__global__ __launch_bounds__(256) void zero_accu_kernel()
{
    float4* p = reinterpret_cast<float4*>(g_accu);
    float4 z = make_float4(0.f, 0.f, 0.f, 0.f);
    int n4 = NN * MROW / 4;
    for (int i = blockIdx.x * 256 + threadIdx.x; i < n4; i += gridDim.x * 256)
        p[i] = z;
}

__global__ __launch_bounds__(256) void hist_kernel(const int* __restrict__ edge_index)
{
    int e = blockIdx.x * 256 + threadIdx.x;
    if (e < EE) g_rel[e] = atomicAdd(&g_deg[edge_index[e]], 1);
}

// Blocked scan: 256 threads x 40 items, one block.
__global__ __launch_bounds__(256) void scan_kernel()
{
    __shared__ int sP[256];
    int t = threadIdx.x;
    int lo = t * 40, hi = min(lo + 40, NN);
    int sum = 0;
    for (int i = lo; i < hi; ++i) sum += g_deg[i];
    sP[t] = sum;
    __syncthreads();
    for (int off = 1; off < 256; off <<= 1) {
        int v = (t >= off) ? sP[t - off] : 0;
        __syncthreads();
        sP[t] += v;
        __syncthreads();
    }
    int run = sP[t] - sum;   // exclusive prefix
    if (t == 0) g_offs[0] = 0;
    for (int i = lo; i < hi; ++i) { run += g_deg[i]; g_offs[i + 1] = run; }
}

__global__ __launch_bounds__(256) void perm_kernel(const int* __restrict__ edge_index)
{
    int e = blockIdx.x * 256 + threadIdx.x;
    if (e < EE) g_ord[g_offs[edge_index[e]] + g_rel[e]] = e;
}

// Per-node halves of MLP1: Pi = nf@Ws1[0:128]+bs1, Pj = nf@Ws1[128:256].
__global__ __launch_bounds__(64) void proj_kernel(
    const float* __restrict__ nf,
    const float* __restrict__ Ws1, const float* __restrict__ bs1)
{
    int n = blockIdx.x * 64 + threadIdx.x;
    if (n >= NN) return;
    float Pi[HIDD], Pj[HIDD];
    #pragma unroll
    for (int j = 0; j < HIDD; ++j) { Pi[j] = bs1[j]; Pj[j] = 0.f; }
    const float4* x4 = reinterpret_cast<const float4*>(nf + (size_t)n * CC);
    #pragma unroll 1
    for (int k4 = 0; k4 < CC / 4; ++k4) {
        float4 a = x4[k4];
        const float* wi = Ws1 + (4 * k4) * HIDD;
        const float* wj = Ws1 + (CC + 4 * k4) * HIDD;
        #pragma unroll
        for (int j = 0; j < HIDD; ++j) {
            Pi[j] = fmaf(a.x, wi[j], Pi[j]);
            Pi[j] = fmaf(a.y, wi[HIDD + j], Pi[j]);
            Pi[j] = fmaf(a.z, wi[2 * HIDD + j], Pi[j]);
            Pi[j] = fmaf(a.w, wi[3 * HIDD + j], Pi[j]);
            Pj[j] = fmaf(a.x, wj[j], Pj[j]);
            Pj[j] = fmaf(a.y, wj[HIDD + j], Pj[j]);
            Pj[j] = fmaf(a.z, wj[2 * HIDD + j], Pj[j]);
            Pj[j] = fmaf(a.w, wj[3 * HIDD + j], Pj[j]);
        }
    }
    float* o = g_proj + (size_t)n * 64;
    #pragma unroll
    for (int j = 0; j < HIDD; ++j) { o[j] = Pi[j]; o[HIDD + j] = Pj[j]; }
}

// One 128-col section: lane owns cols (2l, 2l+1); weights live in 128 VGPRs;
// streams 64 sorted edges (h via broadcast b128 from LDS), accumulates per-
// segment in registers, flushes wave-coalesced atomics into g_accu.
template<int K, int YB, int MOFF>
__device__ __forceinline__ void section_pass(
    int sec, int l,
    const float2* __restrict__ nf2,
    const float* __restrict__ Ws2, const float* __restrict__ bs2,
    const float* __restrict__ Wr2, const float* __restrict__ br2,
    const float (*__restrict__ sH)[68], const float (*__restrict__ sY)[9],
    const int* __restrict__ sSrc, const int* __restrict__ sDst)
{
    float2 Wp[HIDD], Rp[HIDD];
    #pragma unroll
    for (int j = 0; j < HIDD; ++j) {
        Wp[j] = *reinterpret_cast<const float2*>(&Ws2[j * WND + sec * 128 + 2 * l]);
        Rp[j] = *reinterpret_cast<const float2*>(&Wr2[j * WND + sec * 128 + 2 * l]);
    }
    float2 bsv = *reinterpret_cast<const float2*>(&bs2[sec * 128 + 2 * l]);
    float2 brv = *reinterpret_cast<const float2*>(&br2[sec * 128 + 2 * l]);

    float racc0[K], racc1[K];
    #pragma unroll
    for (int k = 0; k < K; ++k) { racc0[k] = 0.f; racc1[k] = 0.f; }
    int cur = sSrc[0];

    #pragma unroll 2
    for (int ee = 0; ee < 64; ++ee) {
        int src = sSrc[ee];                       // broadcast -> wave-uniform
        if (src != cur) {
            float* ab = g_accu + (size_t)cur * MROW + MOFF + 2 * l;
            #pragma unroll
            for (int k = 0; k < K; ++k) {
                unsafeAtomicAdd(ab + k * CC,     racc0[k]);
                unsafeAtomicAdd(ab + k * CC + 1, racc1[k]);
                racc0[k] = 0.f; racc1[k] = 0.f;
            }
            cur = src;
        }
        float2 xj = nf2[(size_t)sDst[ee] * 64 + l];
        float as0 = bsv.x, as1 = bsv.y, ar0 = brv.x, ar1 = brv.y;
        #pragma unroll
        for (int j4 = 0; j4 < 8; ++j4) {
            float4 hsv = *reinterpret_cast<const float4*>(&sH[ee][4 * j4]);
            float4 hrv = *reinterpret_cast<const float4*>(&sH[ee][32 + 4 * j4]);
            as0 = fmaf(hsv.x, Wp[4 * j4 + 0].x, as0); as1 = fmaf(hsv.x, Wp[4 * j4 + 0].y, as1);
            as0 = fmaf(hsv.y, Wp[4 * j4 + 1].x, as0); as1 = fmaf(hsv.y, Wp[4 * j4 + 1].y, as1);
            as0 = fmaf(hsv.z, Wp[4 * j4 + 2].x, as0); as1 = fmaf(hsv.z, Wp[4 * j4 + 2].y, as1);
            as0 = fmaf(hsv.w, Wp[4 * j4 + 3].x, as0); as1 = fmaf(hsv.w, Wp[4 * j4 + 3].y, as1);
            ar0 = fmaf(hrv.x, Rp[4 * j4 + 0].x, ar0); ar1 = fmaf(hrv.x, Rp[4 * j4 + 0].y, ar1);
            ar0 = fmaf(hrv.y, Rp[4 * j4 + 1].x, ar0); ar1 = fmaf(hrv.y, Rp[4 * j4 + 1].y, ar1);
            ar0 = fmaf(hrv.z, Rp[4 * j4 + 2].x, ar0); ar1 = fmaf(hrv.z, Rp[4 * j4 + 2].y, ar1);
            ar0 = fmaf(hrv.w, Rp[4 * j4 + 3].x, ar0); ar1 = fmaf(hrv.w, Rp[4 * j4 + 3].y, ar1);
        }
        float u0 = as0 * ar0 * xj.x;
        float u1 = as1 * ar1 * xj.y;
        #pragma unroll
        for (int k = 0; k < K; ++k) {
            float yv = sY[ee][YB + k];
            racc0[k] = fmaf(u0, yv, racc0[k]);
            racc1[k] = fmaf(u1, yv, racc1[k]);
        }
    }
    float* ab = g_accu + (size_t)cur * MROW + MOFF + 2 * l;
    #pragma unroll
    for (int k = 0; k < K; ++k) {
        unsafeAtomicAdd(ab + k * CC,     racc0[k]);
        unsafeAtomicAdd(ab + k * CC + 1, racc1[k]);
    }
}

// Fused edge MLP2 + tensor-product message + segment-sum. One wave per block,
// 64 sorted edges per block. Prologue computes MLP1 hiddens (lane=edge) into
// LDS; three section passes (lane=2 cols) do the rest entirely in-register.
__global__ __launch_bounds__(64) void fused_kernel(
    const float* __restrict__ nf,
    const float* __restrict__ edge_attr,
    const float* __restrict__ edge_rsh,
    const int*   __restrict__ edge_index,
    const float* __restrict__ Ws2, const float* __restrict__ bs2,
    const float* __restrict__ Wr1, const float* __restrict__ br1,
    const float* __restrict__ Wr2, const float* __restrict__ br2)
{
    __shared__ float sH[64][68];   // 17.4 KB, rows 272B = 16B-aligned
    __shared__ float sY[64][9];    // 2.3 KB
    __shared__ int   sSrc[64], sDst[64];

    int l = threadIdx.x;
    int p = blockIdx.x * 64 + l;   // grid exact: EE/64
    int e = g_ord[p];
    int s = edge_index[e];
    int t = edge_index[EE + e];

    // ---- prologue: hs = silu(Pi[s]+Pj[t]), hr = silu(edge_attr@Wr1+br1)
    {
        float hs[HIDD], hr[HIDD];
        const float4* pi = reinterpret_cast<const float4*>(g_proj + (size_t)s * 64);
        const float4* pj = reinterpret_cast<const float4*>(g_proj + (size_t)t * 64 + HIDD);
        #pragma unroll
        for (int j4 = 0; j4 < HIDD / 4; ++j4) {
            float4 a = pi[j4], b = pj[j4];
            hs[4 * j4 + 0] = silu_f(a.x + b.x);
            hs[4 * j4 + 1] = silu_f(a.y + b.y);
            hs[4 * j4 + 2] = silu_f(a.z + b.z);
            hs[4 * j4 + 3] = silu_f(a.w + b.w);
        }
        #pragma unroll
        for (int j = 0; j < HIDD; ++j) hr[j] = br1[j];
        #pragma unroll 1
        for (int k4 = 0; k4 < RBFD / 4; ++k4) {
            float4 a = reinterpret_cast<const float4*>(edge_attr + (size_t)e * RBFD)[k4];
            const float* wp = Wr1 + (4 * k4) * HIDD;
            #pragma unroll
            for (int j = 0; j < HIDD; ++j) {
                hr[j] = fmaf(a.x, wp[j], hr[j]);
                hr[j] = fmaf(a.y, wp[HIDD + j], hr[j]);
                hr[j] = fmaf(a.z, wp[2 * HIDD + j], hr[j]);
                hr[j] = fmaf(a.w, wp[3 * HIDD + j], hr[j]);
            }
        }
        #pragma unroll
        for (int j4 = 0; j4 < HIDD / 4; ++j4) {
            *reinterpret_cast<float4*>(&sH[l][4 * j4]) =
                make_float4(hs[4 * j4], hs[4 * j4 + 1], hs[4 * j4 + 2], hs[4 * j4 + 3]);
            float h0 = silu_f(hr[4 * j4]),     h1 = silu_f(hr[4 * j4 + 1]);
            float h2 = silu_f(hr[4 * j4 + 2]), h3 = silu_f(hr[4 * j4 + 3]);
            *reinterpret_cast<float4*>(&sH[l][32 + 4 * j4]) = make_float4(h0, h1, h2, h3);
        }
        sSrc[l] = s;
        sDst[l] = t;
        #pragma unroll
        for (int i = 0; i < 9; ++i) sY[l][i] = edge_rsh[(size_t)e * 9 + i];
    }
    __syncthreads();

    const float2* nf2 = reinterpret_cast<const float2*>(nf);
    section_pass<1, 0, 0>     (0, l, nf2, Ws2, bs2, Wr2, br2, sH, sY, sSrc, sDst);
    section_pass<3, 1, CC>    (1, l, nf2, Ws2, bs2, Wr2, br2, sH, sY, sSrc, sDst);
    section_pass<5, 4, 4 * CC>(2, l, nf2, Ws2, bs2, Wr2, br2, sH, sY, sSrc, sDst);
}

// Node-wise linear, 2 nodes per block. (unchanged)
__global__ __launch_bounds__(256) void lin2_kernel(
    const float* __restrict__ W0, const float* __restrict__ b0,
    const float* __restrict__ W1, const float* __restrict__ W2,
    float* __restrict__ out)
{
    __shared__ float sA[2 * MROW];
    int n0 = blockIdx.x * 2;
    const float4* g = reinterpret_cast<const float4*>(g_accu + (size_t)n0 * MROW);
    for (int i = threadIdx.x; i < 2 * MROW / 4; i += 256)
        reinterpret_cast<float4*>(sA)[i] = g[i];
    __syncthreads();

    int d  = threadIdx.x & (CC - 1);
    int nl = threadIdx.x >> 7;
    const float* a = sA + nl * MROW;

    float acc[9];
    #pragma unroll
    for (int m = 0; m < 9; ++m) acc[m] = 0.f;

    #pragma unroll 2
    for (int cc = 0; cc < CC; ++cc) {
        float w0 = W0[cc * CC + d];
        float w1 = W1[cc * CC + d];
        float w2 = W2[cc * CC + d];
        acc[0] = fmaf(a[cc],           w0, acc[0]);
        acc[1] = fmaf(a[CC + cc],      w1, acc[1]);
        acc[2] = fmaf(a[2 * CC + cc],  w1, acc[2]);
        acc[3] = fmaf(a[3 * CC + cc],  w1, acc[3]);
        acc[4] = fmaf(a[4 * CC + cc],  w2, acc[4]);
        acc[5] = fmaf(a[5 * CC + cc],  w2, acc[5]);
        acc[6] = fmaf(a[6 * CC + cc],  w2, acc[6]);
        acc[7] = fmaf(a[7 * CC + cc],  w2, acc[7]);
        acc[8] = fmaf(a[8 * CC + cc],  w2, acc[8]);
    }

    const float inv = 0.08838834764831845f;  // 1/sqrt(128)
    size_t ob = (size_t)(n0 + nl) * MROW;
    out[ob + d] = acc[0] * inv + b0[d];
    #pragma unroll
    for (int m = 0; m < 3; ++m) out[ob + CC + d * 3 + m]     = acc[1 + m] * inv;
    #pragma unroll
    for (int m = 0; m < 5; ++m) out[ob + 4 * CC + d * 5 + m] = acc[4 + m] * inv;
}

extern "C" void kernel_launch(void* const* d_in, const int* in_sizes, int n_in,
                              void* d_out, int out_size, void* d_ws, size_t ws_size,
                              hipStream_t stream)
{
    const float* node_feat  = (const float*)d_in[0];
    const float* edge_attr  = (const float*)d_in[1];
    const float* edge_rsh   = (const float*)d_in[2];
    const int*   edge_index = (const int*)  d_in[3];
    const float* Ws1 = (const float*)d_in[4];
    const float* bs1 = (const float*)d_in[5];
    const float* Ws2 = (const float*)d_in[6];
    const float* bs2 = (const float*)d_in[7];
    const float* Wr1 = (const float*)d_in[8];
    const float* br1 = (const float*)d_in[9];
    const float* Wr2 = (const float*)d_in[10];
    const float* br2 = (const float*)d_in[11];
    const float* W0  = (const float*)d_in[12];
    const float* b0  = (const float*)d_in[13];
    const float* W1  = (const float*)d_in[14];
    const float* W2  = (const float*)d_in[15];
    float* out = (float*)d_out;

    zero_deg_kernel<<<(NN + 255) / 256, 256, 0, stream>>>();
    hist_kernel<<<EE / 256, 256, 0, stream>>>(edge_index);
    scan_kernel<<<1, 256, 0, stream>>>();
    perm_kernel<<<EE / 256, 256, 0, stream>>>(edge_index);
    proj_kernel<<<(NN + 63) / 64, 64, 0, stream>>>(node_feat, Ws1, bs1);
    zero_accu_kernel<<<2048, 256, 0, stream>>>();
    fused_kernel<<<EE / 64, 64, 0, stream>>>(
        node_feat, edge_attr, edge_rsh, edge_index,
        Ws2, bs2, Wr1, br1, Wr2, br2);
    lin2_kernel<<<NN / 2, 256, 0, stream>>>(W0, b0, W1, W2, out);
}